// Round 1
// baseline (262.613 us; speedup 1.0000x reference)
//
#include <hip/hip_runtime.h>
#include <math.h>

#define UU 208
#define VV 176
#define NIMG 256           // B*C = 32*8
#define NPIX (UU*VV)       // 36608

typedef float2 cf;

__device__ __forceinline__ cf mkc(float x, float y){ cf r; r.x = x; r.y = y; return r; }
__device__ __forceinline__ cf cadd(cf a, cf b){ return mkc(a.x + b.x, a.y + b.y); }
__device__ __forceinline__ cf csub(cf a, cf b){ return mkc(a.x - b.x, a.y - b.y); }

// multiply a by table twiddle w (forward table entries e^{-2pi i j/N}); conjugate for inverse
template<bool INV>
__device__ __forceinline__ cf cmulw(cf a, cf w){
  float wy = INV ? -w.y : w.y;
  return mkc(a.x*w.x - a.y*wy, a.x*wy + a.y*w.x);
}
// multiply by compile-time twiddle (wx, wy_fwd) with conj for inverse
template<bool INV>
__device__ __forceinline__ cf cmulc(cf a, float wx, float wy_fwd){
  float wy = INV ? -wy_fwd : wy_fwd;
  return mkc(a.x*wx - a.y*wy, a.x*wy + a.y*wx);
}

template<bool INV>
__device__ __forceinline__ void dft4(cf& x0, cf& x1, cf& x2, cf& x3){
  cf s0 = cadd(x0, x2), d0 = csub(x0, x2);
  cf s1 = cadd(x1, x3), d1 = csub(x1, x3);
  // forward: -i*d1 = (d1.y, -d1.x); inverse: +i*d1
  cf jd1 = INV ? mkc(-d1.y, d1.x) : mkc(d1.y, -d1.x);
  x0 = cadd(s0, s1); x2 = csub(s0, s1);
  x1 = cadd(d0, jd1); x3 = csub(d0, jd1);
}

// 16-point FFT, input x[n] in v[n], output Y[j] at v[4*(j&3) + (j>>2)] (digit-swapped)
template<bool INV>
__device__ __forceinline__ void fft16(cf v[16]){
  dft4<INV>(v[0], v[4], v[8],  v[12]);
  dft4<INV>(v[1], v[5], v[9],  v[13]);
  dft4<INV>(v[2], v[6], v[10], v[14]);
  dft4<INV>(v[3], v[7], v[11], v[15]);
  const float C1 = 0.92387953251128674f;   // cos(pi/8)
  const float S1 = 0.38268343236508978f;   // sin(pi/8)
  const float R2 = 0.70710678118654752f;   // sqrt(2)/2
  // v[b+4c] *= W16^{b*c}
  v[5]  = cmulc<INV>(v[5],  C1, -S1);  // W^1
  v[9]  = cmulc<INV>(v[9],  R2, -R2);  // W^2
  v[13] = cmulc<INV>(v[13], S1, -C1);  // W^3
  v[6]  = cmulc<INV>(v[6],  R2, -R2);  // W^2
  v[10] = cmulc<INV>(v[10], 0.f, -1.f);// W^4
  v[14] = cmulc<INV>(v[14], -R2, -R2); // W^6
  v[7]  = cmulc<INV>(v[7],  S1, -C1);  // W^3
  v[11] = cmulc<INV>(v[11], -R2, -R2); // W^6
  v[15] = cmulc<INV>(v[15], -C1,  S1); // W^9
  dft4<INV>(v[0],  v[1],  v[2],  v[3]);
  dft4<INV>(v[4],  v[5],  v[6],  v[7]);
  dft4<INV>(v[8],  v[9],  v[10], v[11]);
  dft4<INV>(v[12], v[13], v[14], v[15]);
}

// ---------------- twiddle tables ----------------
__global__ __launch_bounds__(256) void twid_init(cf* __restrict__ W176g, cf* __restrict__ W208g){
  int i = threadIdx.x;
  const double PI2 = 6.283185307179586476925286766559;
  if (i < VV){ double a = -PI2 * (double)i / (double)VV; W176g[i] = mkc((float)cos(a), (float)sin(a)); }
  if (i < UU){ double a = -PI2 * (double)i / (double)UU; W208g[i] = mkc((float)cos(a), (float)sin(a)); }
}

// ---------------- mask r values (fp64, faithful to dft2d real part) ----------------
__global__ __launch_bounds__(256) void mask_r(const float* __restrict__ kin, float* __restrict__ rbuf){
  int i = blockIdx.x * 256 + threadIdx.x;
  if (i >= NPIX) return;
  int l = i / VV, k = i - l * VV;
  int rm[6] = {0, 1, 2, 2, 1, 0};
  const double PI2 = 6.283185307179586476925286766559;
  double s = 0.0;
  #pragma unroll
  for (int m = 0; m < 6; m++){
    #pragma unroll
    for (int n = 0; n < 6; n++){
      double ang = PI2 * ((double)(k*m)/(double)VV + (double)(l*n)/(double)UU);
      s += (double)kin[rm[m]*3 + rm[n]] * cos(ang);
    }
  }
  rbuf[i] = (float)(s / 36.0);
}

// ---------------- radix-select: k-th smallest (k=18304) -> threshold ----------------
__global__ __launch_bounds__(256) void select_thr(const float* __restrict__ rbuf, float* __restrict__ thrOut){
  __shared__ unsigned cnt[256];
  __shared__ unsigned sPrefix;
  __shared__ int sK;
  if (threadIdx.x == 0){ sPrefix = 0u; sK = 18304; }
  for (int shift = 24; shift >= 0; shift -= 8){
    for (int b = threadIdx.x; b < 256; b += 256) cnt[b] = 0u;
    __syncthreads();
    unsigned pfx = sPrefix;
    int hi = shift + 8;
    for (int i = threadIdx.x; i < NPIX; i += 256){
      unsigned u = __float_as_uint(rbuf[i]);
      u = (u & 0x80000000u) ? ~u : (u | 0x80000000u);
      if (hi == 32 || (u >> hi) == (pfx >> hi))
        atomicAdd(&cnt[(u >> shift) & 255u], 1u);
    }
    __syncthreads();
    if (threadIdx.x == 0){
      int k = sK; unsigned cum = 0; unsigned b = 0;
      for (; b < 256; b++){ if (cum + cnt[b] > (unsigned)k) break; cum += cnt[b]; }
      sK = k - (int)cum;
      sPrefix = pfx | (b << shift);
    }
    __syncthreads();
  }
  if (threadIdx.x == 0){
    unsigned u = sPrefix;
    u = (u & 0x80000000u) ? (u ^ 0x80000000u) : ~u;
    thrOut[0] = __uint_as_float(u);
  }
}

// ---------------- row FFT forward (length 176 = 16 x 11), real input ----------------
__global__ __launch_bounds__(256) void rowfft_fwd(const float* __restrict__ x, cf* __restrict__ freq,
                                                  const cf* __restrict__ W176g){
  __shared__ cf w176[VV];
  __shared__ cf mid[16][177];
  for (int i = threadIdx.x; i < VV; i += 256) w176[i] = W176g[i];
  const int grp = threadIdx.x >> 4, ln = threadIdx.x & 15;
  const long row = (long)blockIdx.x * 16 + grp;   // < 53248
  const float* xr = x + row * VV;
  cf* fr = freq + row * VV;
  __syncthreads();
  if (ln < 11){
    cf v[16];
    #pragma unroll
    for (int a = 0; a < 16; a++) v[a] = mkc(xr[11*a + ln], 0.f);
    fft16<false>(v);
    #pragma unroll
    for (int j = 0; j < 16; j++)
      mid[grp][j*11 + ln] = cmulw<false>(v[4*(j&3) + (j>>2)], w176[ln*j]);
  }
  __syncthreads();
  cf t[11];
  #pragma unroll
  for (int n2 = 0; n2 < 11; n2++) t[n2] = mid[grp][ln*11 + n2];
  #pragma unroll
  for (int k2 = 0; k2 < 11; k2++){
    cf acc = t[0];
    #pragma unroll
    for (int n2 = 1; n2 < 11; n2++){
      int idx = (n2 * k2) % 11;
      acc = cadd(acc, cmulw<false>(t[n2], w176[16*idx]));
    }
    fr[ln + 16*k2] = acc;
  }
}

// ---------------- fused column FFT (208 = 16 x 13) * mask * column IFFT ----------------
__global__ __launch_bounds__(256) void colfft(cf* __restrict__ freq, const cf* __restrict__ W208g,
                                              const float* __restrict__ rbuf, const float* __restrict__ thrp){
  __shared__ cf w208[UU];
  __shared__ cf buf[UU*17];
  for (int i = threadIdx.x; i < UU; i += 256) w208[i] = W208g[i];
  const int role = threadIdx.x >> 4, c = threadIdx.x & 15;
  const int img = blockIdx.x / 11;
  const int v0 = (blockIdx.x - img*11) << 4;
  cf* base = freq + (size_t)img * NPIX + v0;      // element (u, v0+c) at base[u*VV + c]
  const float thr = thrp[0];
  __syncthreads();
  // Phase A: inner 16-pt forward DFTs (n2 = role < 13), twiddle, -> buf[(j*13+role)][c]
  if (role < 13){
    cf v[16];
    #pragma unroll
    for (int a = 0; a < 16; a++) v[a] = base[(13*a + role)*VV + c];
    fft16<false>(v);
    #pragma unroll
    for (int j = 0; j < 16; j++)
      buf[(j*13 + role)*17 + c] = cmulw<false>(v[4*(j&3) + (j>>2)], w208[role*j]);
  }
  __syncthreads();
  // Phase B: 13-pt DFT (k1 = role), mask multiply, stage in regs
  cf F[13];
  {
    cf t[13];
    #pragma unroll
    for (int n2 = 0; n2 < 13; n2++) t[n2] = buf[(role*13 + n2)*17 + c];
    #pragma unroll
    for (int k2 = 0; k2 < 13; k2++){
      cf acc = t[0];
      #pragma unroll
      for (int n2 = 1; n2 < 13; n2++){
        int idx = (n2 * k2) % 13;
        acc = cadd(acc, cmulw<false>(t[n2], w208[16*idx]));
      }
      int u = role + 16*k2;
      float m = (rbuf[u*VV + v0 + c] > thr) ? 1.0f : 0.0f;
      F[k2] = mkc(acc.x * m, acc.y * m);
    }
  }
  __syncthreads();              // all reads of buf complete
  #pragma unroll
  for (int k2 = 0; k2 < 13; k2++) buf[(role + 16*k2)*17 + c] = F[k2];   // buf now F[u][c]
  __syncthreads();
  // Phase C: inner 16-pt inverse DFTs
  cf vc[16];
  if (role < 13){
    #pragma unroll
    for (int a = 0; a < 16; a++) vc[a] = buf[(13*a + role)*17 + c];
    fft16<true>(vc);
    #pragma unroll
    for (int j = 0; j < 16; j++)
      vc[4*(j&3) + (j>>2)] = cmulw<true>(vc[4*(j&3) + (j>>2)], w208[role*j]);
  }
  __syncthreads();              // reads done before overwrite
  if (role < 13){
    #pragma unroll
    for (int j = 0; j < 16; j++) buf[(j*13 + role)*17 + c] = vc[4*(j&3) + (j>>2)];
  }
  __syncthreads();
  // Phase D: 13-pt inverse DFT, write spatial column back to global (unscaled)
  {
    cf t[13];
    #pragma unroll
    for (int n2 = 0; n2 < 13; n2++) t[n2] = buf[(role*13 + n2)*17 + c];
    #pragma unroll
    for (int k2 = 0; k2 < 13; k2++){
      cf acc = t[0];
      #pragma unroll
      for (int n2 = 1; n2 < 13; n2++){
        int idx = (n2 * k2) % 13;
        acc = cadd(acc, cmulw<true>(t[n2], w208[16*idx]));
      }
      base[(role + 16*k2)*VV + c] = acc;
    }
  }
}

// ---------------- row IFFT + abs + scale ----------------
__global__ __launch_bounds__(256) void rowifft_abs(const cf* __restrict__ freq, float* __restrict__ out,
                                                   const cf* __restrict__ W176g){
  __shared__ cf w176[VV];
  __shared__ cf mid[16][177];
  for (int i = threadIdx.x; i < VV; i += 256) w176[i] = W176g[i];
  const int grp = threadIdx.x >> 4, ln = threadIdx.x & 15;
  const long row = (long)blockIdx.x * 16 + grp;
  const cf* fr = freq + row * VV;
  float* orow = out + row * VV;
  __syncthreads();
  if (ln < 11){
    cf v[16];
    #pragma unroll
    for (int a = 0; a < 16; a++) v[a] = fr[11*a + ln];
    fft16<true>(v);
    #pragma unroll
    for (int j = 0; j < 16; j++)
      mid[grp][j*11 + ln] = cmulw<true>(v[4*(j&3) + (j>>2)], w176[ln*j]);
  }
  __syncthreads();
  cf t[11];
  #pragma unroll
  for (int n2 = 0; n2 < 11; n2++) t[n2] = mid[grp][ln*11 + n2];
  #pragma unroll
  for (int k2 = 0; k2 < 11; k2++){
    cf acc = t[0];
    #pragma unroll
    for (int n2 = 1; n2 < 11; n2++){
      int idx = (n2 * k2) % 11;
      acc = cadd(acc, cmulw<true>(t[n2], w176[16*idx]));
    }
    orow[ln + 16*k2] = sqrtf(acc.x*acc.x + acc.y*acc.y) * (1.0f / 36608.0f);
  }
}

extern "C" void kernel_launch(void* const* d_in, const int* in_sizes, int n_in,
                              void* d_out, int out_size, void* d_ws, size_t ws_size,
                              hipStream_t stream){
  const float* x   = (const float*)d_in[0];   // (32,8,208,176) f32
  const float* kin = (const float*)d_in[1];   // (3,3,1,1) f32
  float* out = (float*)d_out;
  char* ws = (char*)d_ws;
  // workspace layout
  cf*    freq  = (cf*)ws;                         // 256*36608 cf = 74,973,184 B
  float* rbuf  = (float*)(ws + 74973184);         // 36608 f32
  float* thr   = (float*)(ws + 75119616);         // 1 f32 (+pad)
  cf*    W176g = (cf*)(ws + 75119632);            // 176 cf
  cf*    W208g = (cf*)(ws + 75121040);            // 208 cf

  hipLaunchKernelGGL(twid_init,   dim3(1),    dim3(256), 0, stream, W176g, W208g);
  hipLaunchKernelGGL(mask_r,      dim3(143),  dim3(256), 0, stream, kin, rbuf);
  hipLaunchKernelGGL(select_thr,  dim3(1),    dim3(256), 0, stream, rbuf, thr);
  hipLaunchKernelGGL(rowfft_fwd,  dim3(3328), dim3(256), 0, stream, x, freq, W176g);
  hipLaunchKernelGGL(colfft,      dim3(2816), dim3(256), 0, stream, freq, W208g, rbuf, thr);
  hipLaunchKernelGGL(rowifft_abs, dim3(3328), dim3(256), 0, stream, freq, out, W176g);
}

// Round 2
// 179.020 us; speedup vs baseline: 1.4669x; 1.4669x over previous
//
#include <hip/hip_runtime.h>
#include <math.h>

#define UU 208
#define VV 176
#define NIMG 256           // B*C = 32*8
#define NPIX (UU*VV)       // 36608

typedef float2 cf;

__device__ __forceinline__ cf mkc(float x, float y){ cf r; r.x = x; r.y = y; return r; }
__device__ __forceinline__ cf cadd(cf a, cf b){ return mkc(a.x + b.x, a.y + b.y); }
__device__ __forceinline__ cf csub(cf a, cf b){ return mkc(a.x - b.x, a.y - b.y); }

// multiply a by table twiddle w (forward table entries e^{-2pi i j/N}); conjugate for inverse
template<bool INV>
__device__ __forceinline__ cf cmulw(cf a, cf w){
  float wy = INV ? -w.y : w.y;
  return mkc(a.x*w.x - a.y*wy, a.x*wy + a.y*w.x);
}
// multiply by compile-time twiddle (wx, wy_fwd) with conj for inverse
template<bool INV>
__device__ __forceinline__ cf cmulc(cf a, float wx, float wy_fwd){
  float wy = INV ? -wy_fwd : wy_fwd;
  return mkc(a.x*wx - a.y*wy, a.x*wy + a.y*wx);
}

template<bool INV>
__device__ __forceinline__ void dft4(cf& x0, cf& x1, cf& x2, cf& x3){
  cf s0 = cadd(x0, x2), d0 = csub(x0, x2);
  cf s1 = cadd(x1, x3), d1 = csub(x1, x3);
  cf jd1 = INV ? mkc(-d1.y, d1.x) : mkc(d1.y, -d1.x);
  x0 = cadd(s0, s1); x2 = csub(s0, s1);
  x1 = cadd(d0, jd1); x3 = csub(d0, jd1);
}

// 16-point FFT, input x[n] in v[n], output Y[j] at v[4*(j&3) + (j>>2)] (digit-swapped)
template<bool INV>
__device__ __forceinline__ void fft16(cf v[16]){
  dft4<INV>(v[0], v[4], v[8],  v[12]);
  dft4<INV>(v[1], v[5], v[9],  v[13]);
  dft4<INV>(v[2], v[6], v[10], v[14]);
  dft4<INV>(v[3], v[7], v[11], v[15]);
  const float C1 = 0.92387953251128674f;   // cos(pi/8)
  const float S1 = 0.38268343236508978f;   // sin(pi/8)
  const float R2 = 0.70710678118654752f;   // sqrt(2)/2
  v[5]  = cmulc<INV>(v[5],  C1, -S1);  // W^1
  v[9]  = cmulc<INV>(v[9],  R2, -R2);  // W^2
  v[13] = cmulc<INV>(v[13], S1, -C1);  // W^3
  v[6]  = cmulc<INV>(v[6],  R2, -R2);  // W^2
  v[10] = cmulc<INV>(v[10], 0.f, -1.f);// W^4
  v[14] = cmulc<INV>(v[14], -R2, -R2); // W^6
  v[7]  = cmulc<INV>(v[7],  S1, -C1);  // W^3
  v[11] = cmulc<INV>(v[11], -R2, -R2); // W^6
  v[15] = cmulc<INV>(v[15], -C1,  S1); // W^9
  dft4<INV>(v[0],  v[1],  v[2],  v[3]);
  dft4<INV>(v[4],  v[5],  v[6],  v[7]);
  dft4<INV>(v[8],  v[9],  v[10], v[11]);
  dft4<INV>(v[12], v[13], v[14], v[15]);
}

// ---------------- twiddle tables + select state init ----------------
__global__ __launch_bounds__(256) void twid_init(cf* __restrict__ W176g, cf* __restrict__ W208g,
                                                 unsigned* __restrict__ bins, unsigned* __restrict__ state){
  int i = threadIdx.x;
  const double PI2 = 6.283185307179586476925286766559;
  if (i < VV){ double a = -PI2 * (double)i / (double)VV; W176g[i] = mkc((float)cos(a), (float)sin(a)); }
  if (i < UU){ double a = -PI2 * (double)i / (double)UU; W208g[i] = mkc((float)cos(a), (float)sin(a)); }
  bins[i] = 0u;
  if (i == 0){ state[0] = 0u; state[1] = 18304u; }
}

__device__ __forceinline__ unsigned sortable(float f){
  unsigned u = __float_as_uint(f);
  return (u & 0x80000000u) ? ~u : (u | 0x80000000u);
}

// ---------------- mask r values (fp64, faithful to dft2d real part) + pass-0 hist ----------------
__global__ __launch_bounds__(256) void mask_r(const float* __restrict__ kin, float* __restrict__ rbuf,
                                              unsigned* __restrict__ bins){
  __shared__ unsigned h[256];
  h[threadIdx.x] = 0u;
  int i = blockIdx.x * 256 + threadIdx.x;      // grid exactly covers NPIX
  int l = i / VV, k = i - l * VV;
  int rm[6] = {0, 1, 2, 2, 1, 0};
  const double PI2 = 6.283185307179586476925286766559;
  double s = 0.0;
  #pragma unroll
  for (int m = 0; m < 6; m++){
    #pragma unroll
    for (int n = 0; n < 6; n++){
      double ang = PI2 * ((double)(k*m)/(double)VV + (double)(l*n)/(double)UU);
      s += (double)kin[rm[m]*3 + rm[n]] * cos(ang);
    }
  }
  float val = (float)(s / 36.0);
  rbuf[i] = val;
  __syncthreads();
  atomicAdd(&h[sortable(val) >> 24], 1u);
  __syncthreads();
  if (h[threadIdx.x]) atomicAdd(&bins[threadIdx.x], h[threadIdx.x]);
}

// ---------------- multi-block radix-select refinement passes ----------------
template<int SHIFT>
__global__ __launch_bounds__(256) void hist_pass(const float* __restrict__ rbuf, unsigned* __restrict__ bins,
                                                 const unsigned* __restrict__ state){
  __shared__ unsigned h[256];
  h[threadIdx.x] = 0u;
  __syncthreads();
  int i = blockIdx.x * 256 + threadIdx.x;
  unsigned pfx = state[0];
  unsigned u = sortable(rbuf[i]);
  if ((u >> (SHIFT + 8)) == (pfx >> (SHIFT + 8)))
    atomicAdd(&h[(u >> SHIFT) & 255u], 1u);
  __syncthreads();
  if (h[threadIdx.x]) atomicAdd(&bins[threadIdx.x], h[threadIdx.x]);
}

template<int SHIFT>
__global__ __launch_bounds__(256) void scan_pass(unsigned* __restrict__ bins, unsigned* __restrict__ state,
                                                 float* __restrict__ thrOut){
  __shared__ unsigned c[256];
  c[threadIdx.x] = bins[threadIdx.x];
  bins[threadIdx.x] = 0u;            // reset for next pass
  __syncthreads();
  if (threadIdx.x == 0){
    unsigned k = state[1];
    unsigned cum = 0, b = 0;
    for (; b < 256; b++){ if (cum + c[b] > k) break; cum += c[b]; }
    state[1] = k - cum;
    unsigned pfx = state[0] | (b << SHIFT);
    state[0] = pfx;
    if (SHIFT == 0){
      unsigned u = pfx;
      u = (u & 0x80000000u) ? (u ^ 0x80000000u) : ~u;
      thrOut[0] = __uint_as_float(u);
    }
  }
}

// ---------------- row FFT forward (length 176 = 16 x 11), real input ----------------
__global__ __launch_bounds__(256) void rowfft_fwd(const float* __restrict__ x, cf* __restrict__ freq,
                                                  const cf* __restrict__ W176g){
  __shared__ cf w176[VV];
  __shared__ cf mid[16][177];
  for (int i = threadIdx.x; i < VV; i += 256) w176[i] = W176g[i];
  const int grp = threadIdx.x >> 4, ln = threadIdx.x & 15;
  const long row = (long)blockIdx.x * 16 + grp;   // < 53248
  const float* xr = x + row * VV;
  cf* fr = freq + row * VV;
  __syncthreads();
  if (ln < 11){
    cf v[16];
    #pragma unroll
    for (int a = 0; a < 16; a++) v[a] = mkc(xr[11*a + ln], 0.f);
    fft16<false>(v);
    #pragma unroll
    for (int j = 0; j < 16; j++)
      mid[grp][j*11 + ln] = cmulw<false>(v[4*(j&3) + (j>>2)], w176[ln*j]);
  }
  __syncthreads();
  cf t[11];
  #pragma unroll
  for (int n2 = 0; n2 < 11; n2++) t[n2] = mid[grp][ln*11 + n2];
  #pragma unroll
  for (int k2 = 0; k2 < 11; k2++){
    cf acc = t[0];
    #pragma unroll
    for (int n2 = 1; n2 < 11; n2++){
      int idx = (n2 * k2) % 11;
      acc = cadd(acc, cmulw<false>(t[n2], w176[16*idx]));
    }
    fr[ln + 16*k2] = acc;
  }
}

// ---------------- fused column FFT (208 = 16 x 13) * mask * column IFFT ----------------
__global__ __launch_bounds__(256) void colfft(cf* __restrict__ freq, const cf* __restrict__ W208g,
                                              const float* __restrict__ rbuf, const float* __restrict__ thrp){
  __shared__ cf w208[UU];
  __shared__ cf buf[UU*17];
  for (int i = threadIdx.x; i < UU; i += 256) w208[i] = W208g[i];
  const int role = threadIdx.x >> 4, c = threadIdx.x & 15;
  const int img = blockIdx.x / 11;
  const int v0 = (blockIdx.x - img*11) << 4;
  cf* base = freq + (size_t)img * NPIX + v0;      // element (u, v0+c) at base[u*VV + c]
  const float thr = thrp[0];
  __syncthreads();
  // Phase A: inner 16-pt forward DFTs (n2 = role < 13), twiddle, -> buf[(j*13+role)][c]
  if (role < 13){
    cf v[16];
    #pragma unroll
    for (int a = 0; a < 16; a++) v[a] = base[(13*a + role)*VV + c];
    fft16<false>(v);
    #pragma unroll
    for (int j = 0; j < 16; j++)
      buf[(j*13 + role)*17 + c] = cmulw<false>(v[4*(j&3) + (j>>2)], w208[role*j]);
  }
  __syncthreads();
  // Phase B: 13-pt DFT (k1 = role), mask multiply, stage in regs
  cf F[13];
  {
    cf t[13];
    #pragma unroll
    for (int n2 = 0; n2 < 13; n2++) t[n2] = buf[(role*13 + n2)*17 + c];
    #pragma unroll
    for (int k2 = 0; k2 < 13; k2++){
      cf acc = t[0];
      #pragma unroll
      for (int n2 = 1; n2 < 13; n2++){
        int idx = (n2 * k2) % 13;
        acc = cadd(acc, cmulw<false>(t[n2], w208[16*idx]));
      }
      int u = role + 16*k2;
      float m = (rbuf[u*VV + v0 + c] > thr) ? 1.0f : 0.0f;
      F[k2] = mkc(acc.x * m, acc.y * m);
    }
  }
  __syncthreads();              // all reads of buf complete
  #pragma unroll
  for (int k2 = 0; k2 < 13; k2++) buf[(role + 16*k2)*17 + c] = F[k2];   // buf now F[u][c]
  __syncthreads();
  // Phase C: inner 16-pt inverse DFTs
  cf vc[16];
  if (role < 13){
    #pragma unroll
    for (int a = 0; a < 16; a++) vc[a] = buf[(13*a + role)*17 + c];
    fft16<true>(vc);
    #pragma unroll
    for (int j = 0; j < 16; j++)
      vc[4*(j&3) + (j>>2)] = cmulw<true>(vc[4*(j&3) + (j>>2)], w208[role*j]);
  }
  __syncthreads();              // reads done before overwrite
  if (role < 13){
    #pragma unroll
    for (int j = 0; j < 16; j++) buf[(j*13 + role)*17 + c] = vc[4*(j&3) + (j>>2)];
  }
  __syncthreads();
  // Phase D: 13-pt inverse DFT, write spatial column back to global (unscaled)
  {
    cf t[13];
    #pragma unroll
    for (int n2 = 0; n2 < 13; n2++) t[n2] = buf[(role*13 + n2)*17 + c];
    #pragma unroll
    for (int k2 = 0; k2 < 13; k2++){
      cf acc = t[0];
      #pragma unroll
      for (int n2 = 1; n2 < 13; n2++){
        int idx = (n2 * k2) % 13;
        acc = cadd(acc, cmulw<true>(t[n2], w208[16*idx]));
      }
      base[(role + 16*k2)*VV + c] = acc;
    }
  }
}

// ---------------- row IFFT + abs + scale ----------------
__global__ __launch_bounds__(256) void rowifft_abs(const cf* __restrict__ freq, float* __restrict__ out,
                                                   const cf* __restrict__ W176g){
  __shared__ cf w176[VV];
  __shared__ cf mid[16][177];
  for (int i = threadIdx.x; i < VV; i += 256) w176[i] = W176g[i];
  const int grp = threadIdx.x >> 4, ln = threadIdx.x & 15;
  const long row = (long)blockIdx.x * 16 + grp;
  const cf* fr = freq + row * VV;
  float* orow = out + row * VV;
  __syncthreads();
  if (ln < 11){
    cf v[16];
    #pragma unroll
    for (int a = 0; a < 16; a++) v[a] = fr[11*a + ln];
    fft16<true>(v);
    #pragma unroll
    for (int j = 0; j < 16; j++)
      mid[grp][j*11 + ln] = cmulw<true>(v[4*(j&3) + (j>>2)], w176[ln*j]);
  }
  __syncthreads();
  cf t[11];
  #pragma unroll
  for (int n2 = 0; n2 < 11; n2++) t[n2] = mid[grp][ln*11 + n2];
  #pragma unroll
  for (int k2 = 0; k2 < 11; k2++){
    cf acc = t[0];
    #pragma unroll
    for (int n2 = 1; n2 < 11; n2++){
      int idx = (n2 * k2) % 11;
      acc = cadd(acc, cmulw<true>(t[n2], w176[16*idx]));
    }
    orow[ln + 16*k2] = sqrtf(acc.x*acc.x + acc.y*acc.y) * (1.0f / 36608.0f);
  }
}

extern "C" void kernel_launch(void* const* d_in, const int* in_sizes, int n_in,
                              void* d_out, int out_size, void* d_ws, size_t ws_size,
                              hipStream_t stream){
  const float* x   = (const float*)d_in[0];   // (32,8,208,176) f32
  const float* kin = (const float*)d_in[1];   // (3,3,1,1) f32
  float* out = (float*)d_out;
  char* ws = (char*)d_ws;
  // workspace layout
  cf*       freq  = (cf*)ws;                      // 256*36608 cf = 74,973,184 B
  float*    rbuf  = (float*)(ws + 74973184);      // 36608 f32
  float*    thr   = (float*)(ws + 75119616);      // 1 f32 (+pad)
  cf*       W176g = (cf*)(ws + 75119632);         // 176 cf
  cf*       W208g = (cf*)(ws + 75121040);         // 208 cf -> ends 75122704
  unsigned* bins  = (unsigned*)(ws + 75122704);   // 256 u32
  unsigned* state = (unsigned*)(ws + 75123728);   // {prefix, k}

  hipLaunchKernelGGL(twid_init,     dim3(1),    dim3(256), 0, stream, W176g, W208g, bins, state);
  hipLaunchKernelGGL(mask_r,        dim3(143),  dim3(256), 0, stream, kin, rbuf, bins);
  hipLaunchKernelGGL(scan_pass<24>, dim3(1),    dim3(256), 0, stream, bins, state, thr);
  hipLaunchKernelGGL(hist_pass<16>, dim3(143),  dim3(256), 0, stream, rbuf, bins, state);
  hipLaunchKernelGGL(scan_pass<16>, dim3(1),    dim3(256), 0, stream, bins, state, thr);
  hipLaunchKernelGGL(hist_pass<8>,  dim3(143),  dim3(256), 0, stream, rbuf, bins, state);
  hipLaunchKernelGGL(scan_pass<8>,  dim3(1),    dim3(256), 0, stream, bins, state, thr);
  hipLaunchKernelGGL(hist_pass<0>,  dim3(143),  dim3(256), 0, stream, rbuf, bins, state);
  hipLaunchKernelGGL(scan_pass<0>,  dim3(1),    dim3(256), 0, stream, bins, state, thr);
  hipLaunchKernelGGL(rowfft_fwd,    dim3(3328), dim3(256), 0, stream, x, freq, W176g);
  hipLaunchKernelGGL(colfft,        dim3(2816), dim3(256), 0, stream, freq, W208g, rbuf, thr);
  hipLaunchKernelGGL(rowifft_abs,   dim3(3328), dim3(256), 0, stream, freq, out, W176g);
}

// Round 3
// 172.330 us; speedup vs baseline: 1.5239x; 1.0388x over previous
//
#include <hip/hip_runtime.h>
#include <math.h>

#define UU 208
#define VV 176
#define NIMG 256           // B*C = 32*8
#define NPAIR 128          // planes processed as pairs (real + i*imag)
#define NPIX (UU*VV)       // 36608

typedef float2 cf;

__device__ __forceinline__ cf mkc(float x, float y){ cf r; r.x = x; r.y = y; return r; }
__device__ __forceinline__ cf cadd(cf a, cf b){ return mkc(a.x + b.x, a.y + b.y); }
__device__ __forceinline__ cf csub(cf a, cf b){ return mkc(a.x - b.x, a.y - b.y); }

// multiply a by table twiddle w (forward table entries e^{-2pi i j/N}); conjugate for inverse
template<bool INV>
__device__ __forceinline__ cf cmulw(cf a, cf w){
  float wy = INV ? -w.y : w.y;
  return mkc(a.x*w.x - a.y*wy, a.x*wy + a.y*w.x);
}
template<bool INV>
__device__ __forceinline__ cf cmulc(cf a, float wx, float wy_fwd){
  float wy = INV ? -wy_fwd : wy_fwd;
  return mkc(a.x*wx - a.y*wy, a.x*wy + a.y*wx);
}

template<bool INV>
__device__ __forceinline__ void dft4(cf& x0, cf& x1, cf& x2, cf& x3){
  cf s0 = cadd(x0, x2), d0 = csub(x0, x2);
  cf s1 = cadd(x1, x3), d1 = csub(x1, x3);
  cf jd1 = INV ? mkc(-d1.y, d1.x) : mkc(d1.y, -d1.x);
  x0 = cadd(s0, s1); x2 = csub(s0, s1);
  x1 = cadd(d0, jd1); x3 = csub(d0, jd1);
}

// 16-point FFT, input x[n] in v[n], output Y[j] at v[4*(j&3) + (j>>2)] (digit-swapped)
template<bool INV>
__device__ __forceinline__ void fft16(cf v[16]){
  dft4<INV>(v[0], v[4], v[8],  v[12]);
  dft4<INV>(v[1], v[5], v[9],  v[13]);
  dft4<INV>(v[2], v[6], v[10], v[14]);
  dft4<INV>(v[3], v[7], v[11], v[15]);
  const float C1 = 0.92387953251128674f;
  const float S1 = 0.38268343236508978f;
  const float R2 = 0.70710678118654752f;
  v[5]  = cmulc<INV>(v[5],  C1, -S1);
  v[9]  = cmulc<INV>(v[9],  R2, -R2);
  v[13] = cmulc<INV>(v[13], S1, -C1);
  v[6]  = cmulc<INV>(v[6],  R2, -R2);
  v[10] = cmulc<INV>(v[10], 0.f, -1.f);
  v[14] = cmulc<INV>(v[14], -R2, -R2);
  v[7]  = cmulc<INV>(v[7],  S1, -C1);
  v[11] = cmulc<INV>(v[11], -R2, -R2);
  v[15] = cmulc<INV>(v[15], -C1,  S1);
  dft4<INV>(v[0],  v[1],  v[2],  v[3]);
  dft4<INV>(v[4],  v[5],  v[6],  v[7]);
  dft4<INV>(v[8],  v[9],  v[10], v[11]);
  dft4<INV>(v[12], v[13], v[14], v[15]);
}

// ---------------- twiddle tables + bins init ----------------
__global__ __launch_bounds__(256) void twid_init(cf* __restrict__ W176g, cf* __restrict__ W208g,
                                                 unsigned* __restrict__ binsAll /*4*256*/){
  int i = threadIdx.x;
  const double PI2 = 6.283185307179586476925286766559;
  if (i < VV){ double a = -PI2 * (double)i / (double)VV; W176g[i] = mkc((float)cos(a), (float)sin(a)); }
  if (i < UU){ double a = -PI2 * (double)i / (double)UU; W208g[i] = mkc((float)cos(a), (float)sin(a)); }
  #pragma unroll
  for (int p = 0; p < 4; p++) binsAll[p*256 + i] = 0u;
}

__device__ __forceinline__ unsigned sortable(float f){
  unsigned u = __float_as_uint(f);
  return (u & 0x80000000u) ? ~u : (u | 0x80000000u);
}

// load 256-bin histogram, serial-scan for the k-th element's bucket; updates sK, sets sB
__device__ __forceinline__ void level_scan(const unsigned* __restrict__ bins_g, unsigned* h,
                                           unsigned* sB, unsigned* sK){
  __syncthreads();
  for (int t = threadIdx.x; t < 256; t += 256) h[t] = bins_g[t];
  __syncthreads();
  if (threadIdx.x == 0){
    unsigned k = *sK, cum = 0, b = 0;
    for (; b < 256; b++){ unsigned c = h[b]; if (cum + c > k) break; cum += c; }
    *sK = k - cum; *sB = b;
  }
  __syncthreads();
}

// ---------------- mask r values (fp64, faithful to dft2d real part) + pass-0 hist ----------------
__global__ __launch_bounds__(256) void mask_r(const float* __restrict__ kin, float* __restrict__ rbuf,
                                              unsigned* __restrict__ bins24){
  __shared__ unsigned h[256];
  h[threadIdx.x] = 0u;
  int i = blockIdx.x * 256 + threadIdx.x;      // grid exactly covers NPIX
  int l = i / VV, k = i - l * VV;
  int rm[6] = {0, 1, 2, 2, 1, 0};
  const double PI2 = 6.283185307179586476925286766559;
  double s = 0.0;
  #pragma unroll
  for (int m = 0; m < 6; m++){
    #pragma unroll
    for (int n = 0; n < 6; n++){
      double ang = PI2 * ((double)(k*m)/(double)VV + (double)(l*n)/(double)UU);
      s += (double)kin[rm[m]*3 + rm[n]] * cos(ang);
    }
  }
  float val = (float)(s / 36.0);
  rbuf[i] = val;
  __syncthreads();
  atomicAdd(&h[sortable(val) >> 24], 1u);
  __syncthreads();
  if (h[threadIdx.x]) atomicAdd(&bins24[threadIdx.x], h[threadIdx.x]);
}

// ---------------- radix-select refinement: redundant per-block scans, no separate scan kernels ----
template<int LEVEL>   // 1: bits 23..16, 2: bits 15..8, 3: bits 7..0
__global__ __launch_bounds__(256) void hist_pass(const float* __restrict__ rbuf,
                                                 const unsigned* __restrict__ bins24,
                                                 const unsigned* __restrict__ bins16,
                                                 const unsigned* __restrict__ bins8,
                                                 unsigned* __restrict__ binsOut){
  __shared__ unsigned h[256];
  __shared__ unsigned sB, sK;
  if (threadIdx.x == 0) sK = 18304u;
  unsigned prefix = 0u;
  level_scan(bins24, h, &sB, &sK); prefix |= sB << 24;
  if (LEVEL >= 2){ level_scan(bins16, h, &sB, &sK); prefix |= sB << 16; }
  if (LEVEL >= 3){ level_scan(bins8,  h, &sB, &sK); prefix |= sB << 8; }
  __syncthreads();
  h[threadIdx.x] = 0u;
  __syncthreads();
  const int SHIFT = 24 - 8*LEVEL;
  int i = blockIdx.x * 256 + threadIdx.x;
  unsigned u = sortable(rbuf[i]);
  if ((u >> (SHIFT + 8)) == (prefix >> (SHIFT + 8)))
    atomicAdd(&h[(u >> SHIFT) & 255u], 1u);
  __syncthreads();
  if (h[threadIdx.x]) atomicAdd(&binsOut[threadIdx.x], h[threadIdx.x]);
}

__global__ __launch_bounds__(256) void thr_final(const unsigned* __restrict__ bins24,
                                                 const unsigned* __restrict__ bins16,
                                                 const unsigned* __restrict__ bins8,
                                                 const unsigned* __restrict__ bins0,
                                                 float* __restrict__ thrOut){
  __shared__ unsigned h[256];
  __shared__ unsigned sB, sK;
  if (threadIdx.x == 0) sK = 18304u;
  unsigned prefix = 0u;
  level_scan(bins24, h, &sB, &sK); prefix |= sB << 24;
  level_scan(bins16, h, &sB, &sK); prefix |= sB << 16;
  level_scan(bins8,  h, &sB, &sK); prefix |= sB << 8;
  level_scan(bins0,  h, &sB, &sK); prefix |= sB;
  if (threadIdx.x == 0){
    unsigned u = prefix;
    u = (u & 0x80000000u) ? (u ^ 0x80000000u) : ~u;
    thrOut[0] = __uint_as_float(u);
  }
}

// ---------------- row FFT forward, paired planes: z = x[2p] + i*x[2p+1] ----------------
__global__ __launch_bounds__(256) void rowfft_fwd(const float* __restrict__ x, cf* __restrict__ freq,
                                                  const cf* __restrict__ W176g){
  __shared__ cf w176[VV];
  __shared__ cf mid[16][177];
  for (int i = threadIdx.x; i < VV; i += 256) w176[i] = W176g[i];
  const int grp = threadIdx.x >> 4, ln = threadIdx.x & 15;
  const int row = blockIdx.x * 16 + grp;          // < 128*208 = 26624
  const int p = row / UU, rr = row - p * UU;
  const float* xr1 = x + ((size_t)(2*p) * UU + rr) * VV;
  const float* xr2 = xr1 + (size_t)NPIX;
  cf* fr = freq + (size_t)row * VV;
  __syncthreads();
  if (ln < 11){
    cf v[16];
    #pragma unroll
    for (int a = 0; a < 16; a++) v[a] = mkc(xr1[11*a + ln], xr2[11*a + ln]);
    fft16<false>(v);
    #pragma unroll
    for (int j = 0; j < 16; j++)
      mid[grp][j*11 + ln] = cmulw<false>(v[4*(j&3) + (j>>2)], w176[ln*j]);
  }
  __syncthreads();
  cf t[11];
  #pragma unroll
  for (int n2 = 0; n2 < 11; n2++) t[n2] = mid[grp][ln*11 + n2];
  #pragma unroll
  for (int k2 = 0; k2 < 11; k2++){
    cf acc = t[0];
    #pragma unroll
    for (int n2 = 1; n2 < 11; n2++){
      int idx = (n2 * k2) % 11;
      acc = cadd(acc, cmulw<false>(t[n2], w176[16*idx]));
    }
    fr[ln + 16*k2] = acc;
  }
}

// ---------------- fused column FFT (208 = 16 x 13) * mask * column IFFT ----------------
__global__ __launch_bounds__(256) void colfft(cf* __restrict__ freq, const cf* __restrict__ W208g,
                                              const float* __restrict__ rbuf, const float* __restrict__ thrp){
  __shared__ cf w208[UU];
  __shared__ cf buf[UU*17];
  for (int i = threadIdx.x; i < UU; i += 256) w208[i] = W208g[i];
  const int role = threadIdx.x >> 4, c = threadIdx.x & 15;
  const int img = blockIdx.x / 11;                // pair plane, [0,128)
  const int v0 = (blockIdx.x - img*11) << 4;
  cf* base = freq + (size_t)img * NPIX + v0;      // element (u, v0+c) at base[u*VV + c]
  const float thr = thrp[0];
  __syncthreads();
  // Phase A: inner 16-pt forward DFTs
  if (role < 13){
    cf v[16];
    #pragma unroll
    for (int a = 0; a < 16; a++) v[a] = base[(13*a + role)*VV + c];
    fft16<false>(v);
    #pragma unroll
    for (int j = 0; j < 16; j++)
      buf[(j*13 + role)*17 + c] = cmulw<false>(v[4*(j&3) + (j>>2)], w208[role*j]);
  }
  __syncthreads();
  // Phase B: 13-pt DFT, mask multiply, stage in regs
  cf F[13];
  {
    cf t[13];
    #pragma unroll
    for (int n2 = 0; n2 < 13; n2++) t[n2] = buf[(role*13 + n2)*17 + c];
    #pragma unroll
    for (int k2 = 0; k2 < 13; k2++){
      cf acc = t[0];
      #pragma unroll
      for (int n2 = 1; n2 < 13; n2++){
        int idx = (n2 * k2) % 13;
        acc = cadd(acc, cmulw<false>(t[n2], w208[16*idx]));
      }
      int u = role + 16*k2;
      float m = (rbuf[u*VV + v0 + c] > thr) ? 1.0f : 0.0f;
      F[k2] = mkc(acc.x * m, acc.y * m);
    }
  }
  __syncthreads();
  #pragma unroll
  for (int k2 = 0; k2 < 13; k2++) buf[(role + 16*k2)*17 + c] = F[k2];
  __syncthreads();
  // Phase C: inner 16-pt inverse DFTs
  cf vc[16];
  if (role < 13){
    #pragma unroll
    for (int a = 0; a < 16; a++) vc[a] = buf[(13*a + role)*17 + c];
    fft16<true>(vc);
    #pragma unroll
    for (int j = 0; j < 16; j++)
      vc[4*(j&3) + (j>>2)] = cmulw<true>(vc[4*(j&3) + (j>>2)], w208[role*j]);
  }
  __syncthreads();
  if (role < 13){
    #pragma unroll
    for (int j = 0; j < 16; j++) buf[(j*13 + role)*17 + c] = vc[4*(j&3) + (j>>2)];
  }
  __syncthreads();
  // Phase D: 13-pt inverse DFT, write spatial column back (unscaled)
  {
    cf t[13];
    #pragma unroll
    for (int n2 = 0; n2 < 13; n2++) t[n2] = buf[(role*13 + n2)*17 + c];
    #pragma unroll
    for (int k2 = 0; k2 < 13; k2++){
      cf acc = t[0];
      #pragma unroll
      for (int n2 = 1; n2 < 13; n2++){
        int idx = (n2 * k2) % 13;
        acc = cadd(acc, cmulw<true>(t[n2], w208[16*idx]));
      }
      base[(role + 16*k2)*VV + c] = acc;
    }
  }
}

// ---------------- row IFFT + split pair + abs + scale ----------------
__global__ __launch_bounds__(256) void rowifft_abs(const cf* __restrict__ freq, float* __restrict__ out,
                                                   const cf* __restrict__ W176g){
  __shared__ cf w176[VV];
  __shared__ cf mid[16][177];
  for (int i = threadIdx.x; i < VV; i += 256) w176[i] = W176g[i];
  const int grp = threadIdx.x >> 4, ln = threadIdx.x & 15;
  const int row = blockIdx.x * 16 + grp;          // < 26624
  const int p = row / UU, rr = row - p * UU;
  const cf* fr = freq + (size_t)row * VV;
  float* orow1 = out + ((size_t)(2*p) * UU + rr) * VV;
  float* orow2 = orow1 + (size_t)NPIX;
  __syncthreads();
  if (ln < 11){
    cf v[16];
    #pragma unroll
    for (int a = 0; a < 16; a++) v[a] = fr[11*a + ln];
    fft16<true>(v);
    #pragma unroll
    for (int j = 0; j < 16; j++)
      mid[grp][j*11 + ln] = cmulw<true>(v[4*(j&3) + (j>>2)], w176[ln*j]);
  }
  __syncthreads();
  cf t[11];
  #pragma unroll
  for (int n2 = 0; n2 < 11; n2++) t[n2] = mid[grp][ln*11 + n2];
  #pragma unroll
  for (int k2 = 0; k2 < 11; k2++){
    cf acc = t[0];
    #pragma unroll
    for (int n2 = 1; n2 < 11; n2++){
      int idx = (n2 * k2) % 11;
      acc = cadd(acc, cmulw<true>(t[n2], w176[16*idx]));
    }
    // Re = plane 2p (real output), Im = plane 2p+1 (real output)
    orow1[ln + 16*k2] = fabsf(acc.x) * (1.0f / 36608.0f);
    orow2[ln + 16*k2] = fabsf(acc.y) * (1.0f / 36608.0f);
  }
}

extern "C" void kernel_launch(void* const* d_in, const int* in_sizes, int n_in,
                              void* d_out, int out_size, void* d_ws, size_t ws_size,
                              hipStream_t stream){
  const float* x   = (const float*)d_in[0];   // (32,8,208,176) f32
  const float* kin = (const float*)d_in[1];   // (3,3,1,1) f32
  float* out = (float*)d_out;
  char* ws = (char*)d_ws;
  // workspace layout
  cf*       freq  = (cf*)ws;                      // 128*36608 cf = 37,486,592 B
  float*    rbuf  = (float*)(ws + 37486592);      // 36608 f32 -> ends 37633024
  float*    thr   = (float*)(ws + 37633024);      // 1 f32 (+pad)
  cf*       W176g = (cf*)(ws + 37633040);         // 176 cf
  cf*       W208g = (cf*)(ws + 37634448);         // 208 cf -> ends 37636112
  unsigned* bins  = (unsigned*)(ws + 37636112);   // 4*256 u32: [bins24|bins16|bins8|bins0]
  unsigned* bins24 = bins, *bins16 = bins + 256, *bins8 = bins + 512, *bins0 = bins + 768;

  hipLaunchKernelGGL(twid_init,    dim3(1),    dim3(256), 0, stream, W176g, W208g, bins);
  hipLaunchKernelGGL(mask_r,       dim3(143),  dim3(256), 0, stream, kin, rbuf, bins24);
  hipLaunchKernelGGL(hist_pass<1>, dim3(143),  dim3(256), 0, stream, rbuf, bins24, bins16, bins8, bins16);
  hipLaunchKernelGGL(hist_pass<2>, dim3(143),  dim3(256), 0, stream, rbuf, bins24, bins16, bins8, bins8);
  hipLaunchKernelGGL(hist_pass<3>, dim3(143),  dim3(256), 0, stream, rbuf, bins24, bins16, bins8, bins0);
  hipLaunchKernelGGL(thr_final,    dim3(1),    dim3(256), 0, stream, bins24, bins16, bins8, bins0, thr);
  hipLaunchKernelGGL(rowfft_fwd,   dim3(1664), dim3(256), 0, stream, x, freq, W176g);
  hipLaunchKernelGGL(colfft,       dim3(1408), dim3(256), 0, stream, freq, W208g, rbuf, thr);
  hipLaunchKernelGGL(rowifft_abs,  dim3(1664), dim3(256), 0, stream, freq, out, W176g);
}

// Round 4
// 107.488 us; speedup vs baseline: 2.4432x; 1.6032x over previous
//
#include <hip/hip_runtime.h>
#include <math.h>

#define UU 208
#define VV 176
#define NPIX (UU*VV)       // 36608

typedef float2 cf;

__device__ __forceinline__ cf mkc(float x, float y){ cf r; r.x = x; r.y = y; return r; }
__device__ __forceinline__ cf cadd(cf a, cf b){ return mkc(a.x + b.x, a.y + b.y); }
__device__ __forceinline__ cf csub(cf a, cf b){ return mkc(a.x - b.x, a.y - b.y); }

// multiply a by table twiddle w (forward table e^{-2pi i j/N}); conjugate for inverse
template<bool INV>
__device__ __forceinline__ cf cmulw(cf a, cf w){
  float wy = INV ? -w.y : w.y;
  return mkc(a.x*w.x - a.y*wy, a.x*wy + a.y*w.x);
}
template<bool INV>
__device__ __forceinline__ cf cmulc(cf a, float wx, float wy_fwd){
  float wy = INV ? -wy_fwd : wy_fwd;
  return mkc(a.x*wx - a.y*wy, a.x*wy + a.y*wx);
}

template<bool INV>
__device__ __forceinline__ void dft4(cf& x0, cf& x1, cf& x2, cf& x3){
  cf s0 = cadd(x0, x2), d0 = csub(x0, x2);
  cf s1 = cadd(x1, x3), d1 = csub(x1, x3);
  cf jd1 = INV ? mkc(-d1.y, d1.x) : mkc(d1.y, -d1.x);
  x0 = cadd(s0, s1); x2 = csub(s0, s1);
  x1 = cadd(d0, jd1); x3 = csub(d0, jd1);
}

// 16-point FFT, input x[n] in v[n], output Y[j] at v[4*(j&3) + (j>>2)]
template<bool INV>
__device__ __forceinline__ void fft16(cf v[16]){
  dft4<INV>(v[0], v[4], v[8],  v[12]);
  dft4<INV>(v[1], v[5], v[9],  v[13]);
  dft4<INV>(v[2], v[6], v[10], v[14]);
  dft4<INV>(v[3], v[7], v[11], v[15]);
  const float C1 = 0.92387953251128674f;
  const float S1 = 0.38268343236508978f;
  const float R2 = 0.70710678118654752f;
  v[5]  = cmulc<INV>(v[5],  C1, -S1);
  v[9]  = cmulc<INV>(v[9],  R2, -R2);
  v[13] = cmulc<INV>(v[13], S1, -C1);
  v[6]  = cmulc<INV>(v[6],  R2, -R2);
  v[10] = cmulc<INV>(v[10], 0.f, -1.f);
  v[14] = cmulc<INV>(v[14], -R2, -R2);
  v[7]  = cmulc<INV>(v[7],  S1, -C1);
  v[11] = cmulc<INV>(v[11], -R2, -R2);
  v[15] = cmulc<INV>(v[15], -C1,  S1);
  dft4<INV>(v[0],  v[1],  v[2],  v[3]);
  dft4<INV>(v[4],  v[5],  v[6],  v[7]);
  dft4<INV>(v[8],  v[9],  v[10], v[11]);
  dft4<INV>(v[12], v[13], v[14], v[15]);
}

__device__ __forceinline__ unsigned sortable(float f){
  unsigned u = __float_as_uint(f);
  return (u & 0x80000000u) ? ~u : (u | 0x80000000u);
}

// parallel bucket find: 256 threads, bins_g[256]; finds bucket b containing the
// sK-th element (0-based), rewrites sK relative to bucket start, returns b.
__device__ __forceinline__ unsigned find_bucket(const unsigned* __restrict__ bins_g,
                                                unsigned* sWS, unsigned* sB, unsigned* sK){
  const int t = threadIdx.x, lane = t & 63, wv = t >> 6;
  unsigned c = bins_g[t];
  unsigned v = c;
  #pragma unroll
  for (int d = 1; d < 64; d <<= 1){
    unsigned u = __shfl_up(v, d, 64);
    if (lane >= d) v += u;
  }
  if (lane == 63) sWS[wv] = v;
  __syncthreads();
  unsigned woff = 0;
  #pragma unroll
  for (int j = 0; j < 3; j++) woff += (j < wv) ? sWS[j] : 0u;
  unsigned incl = v + woff, excl = incl - c;
  unsigned k = *sK;
  __syncthreads();
  if (k >= excl && k < incl){ *sB = (unsigned)t; *sK = k - excl; }
  __syncthreads();
  return *sB;
}

// ---------------- mask r values (fp64, faithful) + twiddle tables + pass-0 hist ----------------
__global__ __launch_bounds__(256) void mask_r(const float* __restrict__ kin, float* __restrict__ rbuf,
                                              unsigned* __restrict__ bins24,
                                              cf* __restrict__ W176g, cf* __restrict__ W208g){
  __shared__ unsigned h[256];
  h[threadIdx.x] = 0u;
  const double PI2 = 6.283185307179586476925286766559;
  if (blockIdx.x == 0){
    int i = threadIdx.x;
    if (i < VV){ double a = -PI2 * (double)i / (double)VV; W176g[i] = mkc((float)cos(a), (float)sin(a)); }
    if (i < UU){ double a = -PI2 * (double)i / (double)UU; W208g[i] = mkc((float)cos(a), (float)sin(a)); }
  }
  int i = blockIdx.x * 256 + threadIdx.x;      // grid exactly covers NPIX
  int l = i / VV, k = i - l * VV;
  int rm[6] = {0, 1, 2, 2, 1, 0};
  double s = 0.0;
  #pragma unroll
  for (int m = 0; m < 6; m++){
    #pragma unroll
    for (int n = 0; n < 6; n++){
      double ang = PI2 * ((double)(k*m)/(double)VV + (double)(l*n)/(double)UU);
      s += (double)kin[rm[m]*3 + rm[n]] * cos(ang);
    }
  }
  float val = (float)(s / 36.0);
  rbuf[i] = val;
  __syncthreads();
  atomicAdd(&h[sortable(val) >> 24], 1u);
  __syncthreads();
  if (h[threadIdx.x]) atomicAdd(&bins24[threadIdx.x], h[threadIdx.x]);
}

// ---------------- radix-select refinement (parallel scans) ----------------
template<int LEVEL>   // 1: bits 23..16, 2: bits 15..8, 3: bits 7..0
__global__ __launch_bounds__(256) void hist_pass(const float* __restrict__ rbuf,
                                                 const unsigned* __restrict__ binsAll,
                                                 unsigned* __restrict__ binsOut){
  __shared__ unsigned h[256];
  __shared__ unsigned sWS[4];
  __shared__ unsigned sB, sK;
  if (threadIdx.x == 0) sK = 18304u;
  h[threadIdx.x] = 0u;
  __syncthreads();
  unsigned prefix = find_bucket(binsAll, sWS, &sB, &sK) << 24;
  if (LEVEL >= 2) prefix |= find_bucket(binsAll + 256, sWS, &sB, &sK) << 16;
  if (LEVEL >= 3) prefix |= find_bucket(binsAll + 512, sWS, &sB, &sK) << 8;
  const int SHIFT = 24 - 8*LEVEL;
  int i = blockIdx.x * 256 + threadIdx.x;
  unsigned u = sortable(rbuf[i]);
  if ((u >> (SHIFT + 8)) == (prefix >> (SHIFT + 8)))
    atomicAdd(&h[(u >> SHIFT) & 255u], 1u);
  __syncthreads();
  if (h[threadIdx.x]) atomicAdd(&binsOut[threadIdx.x], h[threadIdx.x]);
}

__global__ __launch_bounds__(256) void thr_final(const unsigned* __restrict__ binsAll,
                                                 float* __restrict__ thrOut){
  __shared__ unsigned sWS[4];
  __shared__ unsigned sB, sK;
  if (threadIdx.x == 0) sK = 18304u;
  __syncthreads();
  unsigned prefix = find_bucket(binsAll,       sWS, &sB, &sK) << 24;
  prefix |= find_bucket(binsAll + 256, sWS, &sB, &sK) << 16;
  prefix |= find_bucket(binsAll + 512, sWS, &sB, &sK) << 8;
  prefix |= find_bucket(binsAll + 768, sWS, &sB, &sK);
  if (threadIdx.x == 0){
    unsigned u = prefix;
    u = (u & 0x80000000u) ? (u ^ 0x80000000u) : ~u;
    thrOut[0] = __uint_as_float(u);
  }
}

// ---------------- row FFT forward, paired planes, wave-autonomous ----------------
__global__ __launch_bounds__(256) void rowfft_fwd(const float* __restrict__ x, cf* __restrict__ freq,
                                                  const cf* __restrict__ W176g){
  __shared__ cf w176[VV];
  __shared__ cf mid[16][177];
  for (int i = threadIdx.x; i < VV; i += 256) w176[i] = W176g[i];
  const int gr = threadIdx.x >> 4, ln = threadIdx.x & 15;   // wave owns rows 4w..4w+3
  const int row = blockIdx.x * 16 + gr;          // < 26624
  const int p = row / UU, rr = row - p * UU;
  const float* xr1 = x + ((size_t)(2*p) * UU + rr) * VV;
  const float* xr2 = xr1 + (size_t)NPIX;
  cf* fr = freq + (size_t)row * VV;
  __syncthreads();                                // tables ready (only barrier)
  if (ln < 11){
    cf v[16];
    #pragma unroll
    for (int a = 0; a < 16; a++) v[a] = mkc(xr1[11*a + ln], xr2[11*a + ln]);
    fft16<false>(v);
    #pragma unroll
    for (int j = 0; j < 16; j++)
      mid[gr][j*11 + ln] = cmulw<false>(v[4*(j&3) + (j>>2)], w176[ln*j]);
  }
  // wave-local handoff: no barrier (mid rows private to this wave)
  cf tw[11];
  #pragma unroll
  for (int m = 0; m < 11; m++) tw[m] = w176[16*m];
  cf t[11];
  #pragma unroll
  for (int n2 = 0; n2 < 11; n2++) t[n2] = mid[gr][ln*11 + n2];
  #pragma unroll
  for (int k2 = 0; k2 < 11; k2++){
    cf acc = t[0];
    #pragma unroll
    for (int n2 = 1; n2 < 11; n2++)
      acc = cadd(acc, cmulw<false>(t[n2], tw[(n2 * k2) % 11]));
    fr[ln + 16*k2] = acc;
  }
}

// ---------------- fused column FFT * mask * column IFFT, wave-autonomous ----------------
__global__ __launch_bounds__(256) void colfft(cf* __restrict__ freq, const cf* __restrict__ W208g,
                                              const float* __restrict__ rbuf, const float* __restrict__ thrp){
  __shared__ cf w208[UU];
  __shared__ cf buf[UU*17];
  for (int i = threadIdx.x; i < UU; i += 256) w208[i] = W208g[i];
  // wave w owns 4 columns; lane = r*4 + g within wave
  const int w = threadIdx.x >> 6;
  const int r = (threadIdx.x >> 2) & 15;          // role [0,16)
  const int g = threadIdx.x & 3;                  // col-in-wave [0,4)
  const int cl = w*4 + g;                         // col-in-block [0,16)
  const int img = blockIdx.x / 11;                // paired plane [0,128)
  const int v0 = (blockIdx.x - img*11) << 4;
  cf* base = freq + (size_t)img * NPIX + v0 + cl; // element (u) at base[u*VV]
  const float thr = thrp[0];
  __syncthreads();                                // tables ready (only barrier)
  // Phase A: inner 16-pt forward DFTs (n1 = r < 13), twiddle -> buf rows j*13+r
  if (r < 13){
    cf v[16];
    #pragma unroll
    for (int a = 0; a < 16; a++) v[a] = base[(13*a + r)*VV];
    fft16<false>(v);
    #pragma unroll
    for (int j = 0; j < 16; j++)
      buf[(j*13 + r)*17 + cl] = cmulw<false>(v[4*(j&3) + (j>>2)], w208[r*j]);
  }
  // register twiddles for the 13-point DFTs
  cf tw[13];
  #pragma unroll
  for (int m = 0; m < 13; m++) tw[m] = w208[16*m];
  // Phase B: 13-pt DFT (k1 = r), mask, write buf rows r+16k2  (wave-local, no barrier)
  {
    cf t[13];
    #pragma unroll
    for (int n2 = 0; n2 < 13; n2++) t[n2] = buf[(r*13 + n2)*17 + cl];
    #pragma unroll
    for (int k2 = 0; k2 < 13; k2++){
      cf acc = t[0];
      #pragma unroll
      for (int n2 = 1; n2 < 13; n2++)
        acc = cadd(acc, cmulw<false>(t[n2], tw[(n2 * k2) % 13]));
      int u = r + 16*k2;
      float m = (rbuf[u*VV + v0 + cl] > thr) ? 1.0f : 0.0f;
      buf[u*17 + cl] = mkc(acc.x * m, acc.y * m);
    }
  }
  // Phase C: inner 16-pt inverse DFTs (wave-local)
  if (r < 13){
    cf v[16];
    #pragma unroll
    for (int a = 0; a < 16; a++) v[a] = buf[(13*a + r)*17 + cl];
    fft16<true>(v);
    #pragma unroll
    for (int j = 0; j < 16; j++)
      buf[(j*13 + r)*17 + cl] = cmulw<true>(v[4*(j&3) + (j>>2)], w208[r*j]);
  }
  // Phase D: 13-pt inverse DFT, store spatial column (wave-local)
  {
    cf t[13];
    #pragma unroll
    for (int n2 = 0; n2 < 13; n2++) t[n2] = buf[(r*13 + n2)*17 + cl];
    #pragma unroll
    for (int k2 = 0; k2 < 13; k2++){
      cf acc = t[0];
      #pragma unroll
      for (int n2 = 1; n2 < 13; n2++)
        acc = cadd(acc, cmulw<true>(t[n2], tw[(n2 * k2) % 13]));
      base[(r + 16*k2)*VV] = acc;
    }
  }
}

// ---------------- row IFFT + split pair + abs + scale, wave-autonomous ----------------
__global__ __launch_bounds__(256) void rowifft_abs(const cf* __restrict__ freq, float* __restrict__ out,
                                                   const cf* __restrict__ W176g){
  __shared__ cf w176[VV];
  __shared__ cf mid[16][177];
  for (int i = threadIdx.x; i < VV; i += 256) w176[i] = W176g[i];
  const int gr = threadIdx.x >> 4, ln = threadIdx.x & 15;
  const int row = blockIdx.x * 16 + gr;
  const int p = row / UU, rr = row - p * UU;
  const cf* fr = freq + (size_t)row * VV;
  float* orow1 = out + ((size_t)(2*p) * UU + rr) * VV;
  float* orow2 = orow1 + (size_t)NPIX;
  __syncthreads();
  if (ln < 11){
    cf v[16];
    #pragma unroll
    for (int a = 0; a < 16; a++) v[a] = fr[11*a + ln];
    fft16<true>(v);
    #pragma unroll
    for (int j = 0; j < 16; j++)
      mid[gr][j*11 + ln] = cmulw<true>(v[4*(j&3) + (j>>2)], w176[ln*j]);
  }
  cf tw[11];
  #pragma unroll
  for (int m = 0; m < 11; m++) tw[m] = w176[16*m];
  cf t[11];
  #pragma unroll
  for (int n2 = 0; n2 < 11; n2++) t[n2] = mid[gr][ln*11 + n2];
  #pragma unroll
  for (int k2 = 0; k2 < 11; k2++){
    cf acc = t[0];
    #pragma unroll
    for (int n2 = 1; n2 < 11; n2++)
      acc = cadd(acc, cmulw<true>(t[n2], tw[(n2 * k2) % 11]));
    orow1[ln + 16*k2] = fabsf(acc.x) * (1.0f / 36608.0f);
    orow2[ln + 16*k2] = fabsf(acc.y) * (1.0f / 36608.0f);
  }
}

extern "C" void kernel_launch(void* const* d_in, const int* in_sizes, int n_in,
                              void* d_out, int out_size, void* d_ws, size_t ws_size,
                              hipStream_t stream){
  const float* x   = (const float*)d_in[0];   // (32,8,208,176) f32
  const float* kin = (const float*)d_in[1];   // (3,3,1,1) f32
  float* out = (float*)d_out;
  char* ws = (char*)d_ws;
  cf*       freq  = (cf*)ws;                      // 128*36608 cf = 37,486,592 B
  float*    rbuf  = (float*)(ws + 37486592);      // 36608 f32
  float*    thr   = (float*)(ws + 37633024);      // 1 f32 (+pad)
  cf*       W176g = (cf*)(ws + 37633040);         // 176 cf
  cf*       W208g = (cf*)(ws + 37634448);         // 208 cf
  unsigned* bins  = (unsigned*)(ws + 37636112);   // 4*256 u32: [b24|b16|b8|b0]

  hipMemsetAsync(bins, 0, 4*256*4, stream);
  hipLaunchKernelGGL(mask_r,       dim3(143),  dim3(256), 0, stream, kin, rbuf, bins, W176g, W208g);
  hipLaunchKernelGGL(hist_pass<1>, dim3(143),  dim3(256), 0, stream, rbuf, bins, bins + 256);
  hipLaunchKernelGGL(hist_pass<2>, dim3(143),  dim3(256), 0, stream, rbuf, bins, bins + 512);
  hipLaunchKernelGGL(hist_pass<3>, dim3(143),  dim3(256), 0, stream, rbuf, bins, bins + 768);
  hipLaunchKernelGGL(thr_final,    dim3(1),    dim3(256), 0, stream, bins, thr);
  hipLaunchKernelGGL(rowfft_fwd,   dim3(1664), dim3(256), 0, stream, x, freq, W176g);
  hipLaunchKernelGGL(colfft,       dim3(1408), dim3(256), 0, stream, freq, W208g, rbuf, thr);
  hipLaunchKernelGGL(rowifft_abs,  dim3(1664), dim3(256), 0, stream, freq, out, W176g);
}

// Round 5
// 95.846 us; speedup vs baseline: 2.7400x; 1.1215x over previous
//
#include <hip/hip_runtime.h>
#include <math.h>

#define UU 208
#define VV 176
#define NPIX (UU*VV)       // 36608

typedef __attribute__((ext_vector_type(2))) float v2f;   // complex: .x=re, .y=im
typedef __attribute__((ext_vector_type(4))) float v4f;   // twiddle: (wx, wy, -wy, wx) fwd / (wx,-wy, wy, wx) inv

__device__ __forceinline__ v2f mk2(float x, float y){ v2f r; r.x = x; r.y = y; return r; }
__device__ __forceinline__ v2f sp(float s){ v2f r; r.x = s; r.y = s; return r; }

// complex mul by compile-time twiddle (wx, wy_fwd), conj for inverse: 1 pk_mul + 1 pk_fma
template<bool INV>
__device__ __forceinline__ v2f cmulc(v2f a, float wx, float wy_fwd){
  const float wy = INV ? -wy_fwd : wy_fwd;
  return sp(a.x) * mk2(wx, wy) + sp(a.y) * mk2(-wy, wx);
}
// complex mul by table entry t=(m0|m1): 1 pk_mul + 1 pk_fma
__device__ __forceinline__ v2f cmulw4(v2f a, v4f t){
  v2f m0 = mk2(t.x, t.y), m1 = mk2(t.z, t.w);
  return sp(a.x) * m0 + sp(a.y) * m1;
}
// acc += a * w  : 2 pk_fma
__device__ __forceinline__ void cmac4(v2f& acc, v2f a, v4f t){
  v2f m0 = mk2(t.x, t.y), m1 = mk2(t.z, t.w);
  acc += sp(a.x) * m0;
  acc += sp(a.y) * m1;
}

template<bool INV>
__device__ __forceinline__ void dft4(v2f& x0, v2f& x1, v2f& x2, v2f& x3){
  v2f s0 = x0 + x2, d0 = x0 - x2;
  v2f s1 = x1 + x3, d1 = x1 - x3;
  v2f jd1;
  if (INV){ jd1.x = -d1.y; jd1.y =  d1.x; }
  else    { jd1.x =  d1.y; jd1.y = -d1.x; }
  x0 = s0 + s1; x2 = s0 - s1;
  x1 = d0 + jd1; x3 = d0 - jd1;
}

// 16-point FFT, input x[n] in v[n], output Y[j] at v[4*(j&3) + (j>>2)]
template<bool INV>
__device__ __forceinline__ void fft16(v2f v[16]){
  dft4<INV>(v[0], v[4], v[8],  v[12]);
  dft4<INV>(v[1], v[5], v[9],  v[13]);
  dft4<INV>(v[2], v[6], v[10], v[14]);
  dft4<INV>(v[3], v[7], v[11], v[15]);
  const float C1 = 0.92387953251128674f;
  const float S1 = 0.38268343236508978f;
  const float R2 = 0.70710678118654752f;
  v[5]  = cmulc<INV>(v[5],  C1, -S1);
  v[9]  = cmulc<INV>(v[9],  R2, -R2);
  v[13] = cmulc<INV>(v[13], S1, -C1);
  v[6]  = cmulc<INV>(v[6],  R2, -R2);
  v[10] = cmulc<INV>(v[10], 0.f, -1.f);
  v[14] = cmulc<INV>(v[14], -R2, -R2);
  v[7]  = cmulc<INV>(v[7],  S1, -C1);
  v[11] = cmulc<INV>(v[11], -R2, -R2);
  v[15] = cmulc<INV>(v[15], -C1,  S1);
  dft4<INV>(v[0],  v[1],  v[2],  v[3]);
  dft4<INV>(v[4],  v[5],  v[6],  v[7]);
  dft4<INV>(v[8],  v[9],  v[10], v[11]);
  dft4<INV>(v[12], v[13], v[14], v[15]);
}

__device__ __forceinline__ unsigned sortable(float f){
  unsigned u = __float_as_uint(f);
  return (u & 0x80000000u) ? ~u : (u | 0x80000000u);
}

// parallel bucket find: 256 threads, bins_g[256]
__device__ __forceinline__ unsigned find_bucket(const unsigned* __restrict__ bins_g,
                                                unsigned* sWS, unsigned* sB, unsigned* sK){
  const int t = threadIdx.x, lane = t & 63, wv = t >> 6;
  unsigned c = bins_g[t];
  unsigned v = c;
  #pragma unroll
  for (int d = 1; d < 64; d <<= 1){
    unsigned u = __shfl_up(v, d, 64);
    if (lane >= d) v += u;
  }
  if (lane == 63) sWS[wv] = v;
  __syncthreads();
  unsigned woff = 0;
  #pragma unroll
  for (int j = 0; j < 3; j++) woff += (j < wv) ? sWS[j] : 0u;
  unsigned incl = v + woff, excl = incl - c;
  unsigned k = *sK;
  __syncthreads();
  if (k >= excl && k < incl){ *sB = (unsigned)t; *sK = k - excl; }
  __syncthreads();
  return *sB;
}

// ---------------- mask r values (fp64, faithful) + twiddle tables + pass-0 hist ----------------
__global__ __launch_bounds__(256) void mask_r(const float* __restrict__ kin, float* __restrict__ rbuf,
                                              unsigned* __restrict__ bins24,
                                              v4f* __restrict__ W176f, v4f* __restrict__ W176i,
                                              v4f* __restrict__ W208f, v4f* __restrict__ W208i){
  __shared__ unsigned h[256];
  h[threadIdx.x] = 0u;
  const double PI2 = 6.283185307179586476925286766559;
  if (blockIdx.x == 0){
    int i = threadIdx.x;
    if (i < VV){
      double a = -PI2 * (double)i / (double)VV;
      float c = (float)cos(a), s = (float)sin(a);
      v4f f; f.x = c; f.y = s; f.z = -s; f.w = c;   W176f[i] = f;
      v4f g; g.x = c; g.y = -s; g.z = s; g.w = c;   W176i[i] = g;
    }
    if (i < UU){
      double a = -PI2 * (double)i / (double)UU;
      float c = (float)cos(a), s = (float)sin(a);
      v4f f; f.x = c; f.y = s; f.z = -s; f.w = c;   W208f[i] = f;
      v4f g; g.x = c; g.y = -s; g.z = s; g.w = c;   W208i[i] = g;
    }
  }
  int i = blockIdx.x * 256 + threadIdx.x;      // grid exactly covers NPIX
  int l = i / VV, k = i - l * VV;
  int rm[6] = {0, 1, 2, 2, 1, 0};
  double s = 0.0;
  #pragma unroll
  for (int m = 0; m < 6; m++){
    #pragma unroll
    for (int n = 0; n < 6; n++){
      double ang = PI2 * ((double)(k*m)/(double)VV + (double)(l*n)/(double)UU);
      s += (double)kin[rm[m]*3 + rm[n]] * cos(ang);
    }
  }
  float val = (float)(s / 36.0);
  rbuf[i] = val;
  __syncthreads();
  atomicAdd(&h[sortable(val) >> 24], 1u);
  __syncthreads();
  if (h[threadIdx.x]) atomicAdd(&bins24[threadIdx.x], h[threadIdx.x]);
}

// ---------------- radix-select refinement (parallel scans) ----------------
template<int LEVEL>
__global__ __launch_bounds__(256) void hist_pass(const float* __restrict__ rbuf,
                                                 const unsigned* __restrict__ binsAll,
                                                 unsigned* __restrict__ binsOut){
  __shared__ unsigned h[256];
  __shared__ unsigned sWS[4];
  __shared__ unsigned sB, sK;
  if (threadIdx.x == 0) sK = 18304u;
  h[threadIdx.x] = 0u;
  __syncthreads();
  unsigned prefix = find_bucket(binsAll, sWS, &sB, &sK) << 24;
  if (LEVEL >= 2) prefix |= find_bucket(binsAll + 256, sWS, &sB, &sK) << 16;
  if (LEVEL >= 3) prefix |= find_bucket(binsAll + 512, sWS, &sB, &sK) << 8;
  const int SHIFT = 24 - 8*LEVEL;
  int i = blockIdx.x * 256 + threadIdx.x;
  unsigned u = sortable(rbuf[i]);
  if ((u >> (SHIFT + 8)) == (prefix >> (SHIFT + 8)))
    atomicAdd(&h[(u >> SHIFT) & 255u], 1u);
  __syncthreads();
  if (h[threadIdx.x]) atomicAdd(&binsOut[threadIdx.x], h[threadIdx.x]);
}

__global__ __launch_bounds__(256) void thr_final(const unsigned* __restrict__ binsAll,
                                                 float* __restrict__ thrOut){
  __shared__ unsigned sWS[4];
  __shared__ unsigned sB, sK;
  if (threadIdx.x == 0) sK = 18304u;
  __syncthreads();
  unsigned prefix = find_bucket(binsAll,       sWS, &sB, &sK) << 24;
  prefix |= find_bucket(binsAll + 256, sWS, &sB, &sK) << 16;
  prefix |= find_bucket(binsAll + 512, sWS, &sB, &sK) << 8;
  prefix |= find_bucket(binsAll + 768, sWS, &sB, &sK);
  if (threadIdx.x == 0){
    unsigned u = prefix;
    u = (u & 0x80000000u) ? (u ^ 0x80000000u) : ~u;
    thrOut[0] = __uint_as_float(u);
  }
}

// ---------------- row FFT forward, paired planes, wave-autonomous ----------------
__global__ __launch_bounds__(256) void rowfft_fwd(const float* __restrict__ x, v2f* __restrict__ freq,
                                                  const v4f* __restrict__ W176f){
  __shared__ v4f wf[VV];
  __shared__ v2f mid[16][177];
  for (int i = threadIdx.x; i < VV; i += 256) wf[i] = W176f[i];
  const int gr = threadIdx.x >> 4, ln = threadIdx.x & 15;
  const int row = blockIdx.x * 16 + gr;          // < 26624
  const int p = row / UU, rr = row - p * UU;
  const float* xr1 = x + ((size_t)(2*p) * UU + rr) * VV;
  const float* xr2 = xr1 + (size_t)NPIX;
  v2f* fr = freq + (size_t)row * VV;
  __syncthreads();                                // tables ready (only barrier)
  if (ln < 11){
    v2f v[16];
    #pragma unroll
    for (int a = 0; a < 16; a++) v[a] = mk2(xr1[11*a + ln], xr2[11*a + ln]);
    fft16<false>(v);
    #pragma unroll
    for (int j = 0; j < 16; j++)
      mid[gr][j*11 + ln] = cmulw4(v[4*(j&3) + (j>>2)], wf[ln*j]);
  }
  v2f t[11];
  #pragma unroll
  for (int n2 = 0; n2 < 11; n2++) t[n2] = mid[gr][ln*11 + n2];
  #pragma unroll
  for (int k2 = 0; k2 < 11; k2++){
    v2f acc = t[0];
    #pragma unroll
    for (int n2 = 1; n2 < 11; n2++)
      cmac4(acc, t[n2], wf[16*((n2 * k2) % 11)]);   // uniform idx -> LDS broadcast
    fr[ln + 16*k2] = acc;
  }
}

// ---------------- fused column FFT * mask * column IFFT, wave-autonomous ----------------
__global__ __launch_bounds__(256) void colfft(v2f* __restrict__ freq,
                                              const v4f* __restrict__ W208f, const v4f* __restrict__ W208i,
                                              const float* __restrict__ rbuf, const float* __restrict__ thrp){
  __shared__ v4f wf[UU];
  __shared__ v4f wi[UU];
  __shared__ v2f buf[UU*17];
  for (int i = threadIdx.x; i < UU; i += 256){ wf[i] = W208f[i]; wi[i] = W208i[i]; }
  const int w = threadIdx.x >> 6;
  const int r = (threadIdx.x >> 2) & 15;          // role [0,16)
  const int g = threadIdx.x & 3;                  // col-in-wave [0,4)
  const int cl = w*4 + g;                         // col-in-block [0,16)
  const int img = blockIdx.x / 11;                // paired plane [0,128)
  const int v0 = (blockIdx.x - img*11) << 4;
  v2f* base = freq + (size_t)img * NPIX + v0 + cl;
  const float thr = thrp[0];
  __syncthreads();                                // tables ready (only barrier)
  // Phase A: inner 16-pt forward DFTs
  if (r < 13){
    v2f v[16];
    #pragma unroll
    for (int a = 0; a < 16; a++) v[a] = base[(13*a + r)*VV];
    fft16<false>(v);
    #pragma unroll
    for (int j = 0; j < 16; j++)
      buf[(j*13 + r)*17 + cl] = cmulw4(v[4*(j&3) + (j>>2)], wf[r*j]);
  }
  // Phase B: 13-pt DFT (k1 = r), mask, write buf rows r+16k2 (wave-local)
  {
    v2f t[13];
    #pragma unroll
    for (int n2 = 0; n2 < 13; n2++) t[n2] = buf[(r*13 + n2)*17 + cl];
    #pragma unroll
    for (int k2 = 0; k2 < 13; k2++){
      v2f acc = t[0];
      #pragma unroll
      for (int n2 = 1; n2 < 13; n2++)
        cmac4(acc, t[n2], wf[16*((n2 * k2) % 13)]);   // uniform -> broadcast
      int u = r + 16*k2;
      float m = (rbuf[u*VV + v0 + cl] > thr) ? 1.0f : 0.0f;
      buf[u*17 + cl] = acc * sp(m);
    }
  }
  // Phase C: inner 16-pt inverse DFTs (wave-local)
  if (r < 13){
    v2f v[16];
    #pragma unroll
    for (int a = 0; a < 16; a++) v[a] = buf[(13*a + r)*17 + cl];
    fft16<true>(v);
    #pragma unroll
    for (int j = 0; j < 16; j++)
      buf[(j*13 + r)*17 + cl] = cmulw4(v[4*(j&3) + (j>>2)], wi[r*j]);
  }
  // Phase D: 13-pt inverse DFT, store spatial column (wave-local)
  {
    v2f t[13];
    #pragma unroll
    for (int n2 = 0; n2 < 13; n2++) t[n2] = buf[(r*13 + n2)*17 + cl];
    #pragma unroll
    for (int k2 = 0; k2 < 13; k2++){
      v2f acc = t[0];
      #pragma unroll
      for (int n2 = 1; n2 < 13; n2++)
        cmac4(acc, t[n2], wi[16*((n2 * k2) % 13)]);   // conj 13th roots
      base[(r + 16*k2)*VV] = acc;
    }
  }
}

// ---------------- row IFFT + split pair + abs + scale, wave-autonomous ----------------
__global__ __launch_bounds__(256) void rowifft_abs(const v2f* __restrict__ freq, float* __restrict__ out,
                                                   const v4f* __restrict__ W176i){
  __shared__ v4f wi[VV];
  __shared__ v2f mid[16][177];
  for (int i = threadIdx.x; i < VV; i += 256) wi[i] = W176i[i];
  const int gr = threadIdx.x >> 4, ln = threadIdx.x & 15;
  const int row = blockIdx.x * 16 + gr;
  const int p = row / UU, rr = row - p * UU;
  const v2f* fr = freq + (size_t)row * VV;
  float* orow1 = out + ((size_t)(2*p) * UU + rr) * VV;
  float* orow2 = orow1 + (size_t)NPIX;
  __syncthreads();
  if (ln < 11){
    v2f v[16];
    #pragma unroll
    for (int a = 0; a < 16; a++) v[a] = fr[11*a + ln];
    fft16<true>(v);
    #pragma unroll
    for (int j = 0; j < 16; j++)
      mid[gr][j*11 + ln] = cmulw4(v[4*(j&3) + (j>>2)], wi[ln*j]);
  }
  v2f t[11];
  #pragma unroll
  for (int n2 = 0; n2 < 11; n2++) t[n2] = mid[gr][ln*11 + n2];
  #pragma unroll
  for (int k2 = 0; k2 < 11; k2++){
    v2f acc = t[0];
    #pragma unroll
    for (int n2 = 1; n2 < 11; n2++)
      cmac4(acc, t[n2], wi[16*((n2 * k2) % 11)]);   // conj 11th roots
    orow1[ln + 16*k2] = fabsf(acc.x) * (1.0f / 36608.0f);
    orow2[ln + 16*k2] = fabsf(acc.y) * (1.0f / 36608.0f);
  }
}

extern "C" void kernel_launch(void* const* d_in, const int* in_sizes, int n_in,
                              void* d_out, int out_size, void* d_ws, size_t ws_size,
                              hipStream_t stream){
  const float* x   = (const float*)d_in[0];   // (32,8,208,176) f32
  const float* kin = (const float*)d_in[1];   // (3,3,1,1) f32
  float* out = (float*)d_out;
  char* ws = (char*)d_ws;
  v2f*      freq  = (v2f*)ws;                     // 128*36608*8 = 37,486,592 B
  float*    rbuf  = (float*)(ws + 37486592);      // 36608 f32
  float*    thr   = (float*)(ws + 37633024);      // 1 f32 (+pad)
  v4f*      W176f = (v4f*)(ws + 37633040);        // 176*16 B
  v4f*      W176i = (v4f*)(ws + 37635856);
  v4f*      W208f = (v4f*)(ws + 37638672);        // 208*16 B
  v4f*      W208i = (v4f*)(ws + 37642000);
  unsigned* bins  = (unsigned*)(ws + 37645328);   // 4*256 u32

  hipMemsetAsync(bins, 0, 4*256*4, stream);
  hipLaunchKernelGGL(mask_r,       dim3(143),  dim3(256), 0, stream, kin, rbuf, bins,
                     W176f, W176i, W208f, W208i);
  hipLaunchKernelGGL(hist_pass<1>, dim3(143),  dim3(256), 0, stream, rbuf, bins, bins + 256);
  hipLaunchKernelGGL(hist_pass<2>, dim3(143),  dim3(256), 0, stream, rbuf, bins, bins + 512);
  hipLaunchKernelGGL(hist_pass<3>, dim3(143),  dim3(256), 0, stream, rbuf, bins, bins + 768);
  hipLaunchKernelGGL(thr_final,    dim3(1),    dim3(256), 0, stream, bins, thr);
  hipLaunchKernelGGL(rowfft_fwd,   dim3(1664), dim3(256), 0, stream, x, freq, W176f);
  hipLaunchKernelGGL(colfft,       dim3(1408), dim3(256), 0, stream, freq, W208f, W208i, rbuf, thr);
  hipLaunchKernelGGL(rowifft_abs,  dim3(1664), dim3(256), 0, stream, freq, out, W176i);
}